// Round 1
// baseline (666.961 us; speedup 1.0000x reference)
//
#include <hip/hip_runtime.h>

// Memory_Module: paste feature tensors into memory tensors at per-batch
// dynamic offsets (Loc), returning updated copies.
//
// Outputs (concat, fp32):
//   out_b : (16,256, 32, 32)  <- mem_bottleneck,     feat (16,256, 8, 8), off = (y>>4, x>>4)
//   out_3 : (16,128, 64, 64)  <- mem_intermediate_3, feat (16,128,16,16), off = (y>>3, x>>3)
//   out_2 : (16, 64,128,128)  <- mem_intermediate_2, feat (16, 64,32,32), off = (y>>2, x>>2)
//   out_1 : (16, 64,256,256)  <- mem_intermediate_1, feat (16, 64,64,64), off = (y>>1, x>>1)
//
// Memory-bound: ~386MB mem read + ~386MB out write + ~24MB feat -> ~820MB.

__global__ void copy_all_kernel(const float4* __restrict__ m0,
                                const float4* __restrict__ m1,
                                const float4* __restrict__ m2,
                                const float4* __restrict__ m3,
                                float4* __restrict__ out) {
    // sizes in float4 units
    const int n0   = 1048576;   // 16*256*32*32 /4
    const int n01  = 3145728;   // + 16*128*64*64 /4   (2097152)
    const int n012 = 7340032;   // + 16*64*128*128 /4  (4194304)
    const int ntot = 24117248;  // + 16*64*256*256 /4  (16777216)
    const int stride = gridDim.x * blockDim.x;
    for (int i = blockIdx.x * blockDim.x + threadIdx.x; i < ntot; i += stride) {
        float4 v;
        if (i < n0)        v = m0[i];
        else if (i < n01)  v = m1[i - n0];
        else if (i < n012) v = m2[i - n01];
        else               v = m3[i - n012];
        out[i] = v;
    }
}

__global__ void scatter_kernel(const int* __restrict__ Loc,
                               const float4* __restrict__ f0,
                               const float4* __restrict__ f1,
                               const float4* __restrict__ f2,
                               const float4* __restrict__ f3,
                               float* __restrict__ out) {
    // feature sizes in float4 units, prefix sums
    const int t0 = 65536;    // 16*256*8*8 /4
    const int t1 = 196608;   // + 16*128*16*16 /4 (131072)
    const int t2 = 458752;   // + 16*64*32*32 /4  (262144)
    const int tt = 1507328;  // + 16*64*64*64 /4  (1048576)
    const int stride = gridDim.x * blockDim.x;
    for (int i = blockIdx.x * blockDim.x + threadIdx.x; i < tt; i += stride) {
        const float4* f; int li, lF, lC, lW, sh, ob;
        if (i < t0)      { f = f0; li = i;      lF = 3; lC = 8; lW = 5; sh = 4; ob = 0; }
        else if (i < t1) { f = f1; li = i - t0; lF = 4; lC = 7; lW = 6; sh = 3; ob = 4194304; }
        else if (i < t2) { f = f2; li = i - t1; lF = 5; lC = 6; lW = 7; sh = 2; ob = 12582912; }
        else             { f = f3; li = i - t2; lF = 6; lC = 6; lW = 8; sh = 1; ob = 29360128; }

        const int flat = li << 2;                 // scalar element index within feat
        const int FWm  = (1 << lF) - 1;           // FH == FW (square)
        const int w = flat & FWm;
        const int h = (flat >> lF) & FWm;
        const int c = (flat >> (2 * lF)) & ((1 << lC) - 1);
        const int b = flat >> (2 * lF + lC);

        const int x = Loc[2 * b];
        const int y = Loc[2 * b + 1];
        const int maxo = (1 << lW) - (1 << lF);   // dynamic_update_slice clamp
        int woff = x >> sh; woff = woff < 0 ? 0 : (woff > maxo ? maxo : woff);
        int hoff = y >> sh; hoff = hoff < 0 ? 0 : (hoff > maxo ? maxo : hoff);

        const float4 v = f[li];
        const int dst = ob + (((b << lC) + c) << (2 * lW)) + ((hoff + h) << lW) + (woff + w);
        // woff is not 4-aligned in general -> scalar stores (w is 4-aligned,
        // so all 4 elements stay within the same row).
        out[dst]     = v.x;
        out[dst + 1] = v.y;
        out[dst + 2] = v.z;
        out[dst + 3] = v.w;
    }
}

extern "C" void kernel_launch(void* const* d_in, const int* in_sizes, int n_in,
                              void* d_out, int out_size, void* d_ws, size_t ws_size,
                              hipStream_t stream) {
    const int*   Loc = (const int*)d_in[0];
    const float* f0  = (const float*)d_in[1];  // bottleneck
    const float* f1  = (const float*)d_in[2];  // intermediate_3
    const float* f2  = (const float*)d_in[3];  // intermediate_2
    const float* f3  = (const float*)d_in[4];  // intermediate_1
    const float* m0  = (const float*)d_in[5];  // mem_bottleneck
    const float* m1  = (const float*)d_in[6];  // mem_intermediate_3
    const float* m2  = (const float*)d_in[7];  // mem_intermediate_2
    const float* m3  = (const float*)d_in[8];  // mem_intermediate_1
    float* out = (float*)d_out;

    // 1) full copy mem -> out (float4, grid-stride)
    copy_all_kernel<<<2048, 256, 0, stream>>>(
        (const float4*)m0, (const float4*)m1, (const float4*)m2, (const float4*)m3,
        (float4*)out);

    // 2) overwrite feature windows (stream-ordered after the copy)
    scatter_kernel<<<2048, 256, 0, stream>>>(
        Loc,
        (const float4*)f0, (const float4*)f1, (const float4*)f2, (const float4*)f3,
        out);
}